// Round 1
// baseline (374.940 us; speedup 1.0000x reference)
//
#include <hip/hip_runtime.h>
#include <hip/hip_bf16.h>

// Problem constants
// B=32, T=512, D=64, V=60
// inputs: [0] input_ids int32 [32*512], [1] repr_tab f32 [60*64*64],
//         [2] W1 f32 [4096*64], [3] b1 f32 [64], [4] W2 f32 [64*60], [5] b2 f32 [60]
// output: logits f32 [32*60]

constexpr int LDP = 68;  // padded LDS row stride (16B-aligned rows, 2-way max bank conflict)

// ---------------- LDS staging helpers ----------------

// Copy a 64x64 f32 matrix (row-major, contiguous) from global into padded LDS.
__device__ __forceinline__ void stage64(float* __restrict__ dst, const float* __restrict__ src, int t) {
    const int i = t >> 2;              // row 0..63
    const int seg = (t & 3) << 4;      // 16-float segment
    const float4* s4 = reinterpret_cast<const float4*>(src + i * 64 + seg);
    float4 r0 = s4[0], r1 = s4[1], r2 = s4[2], r3 = s4[3];
    float4* d = reinterpret_cast<float4*>(dst + i * LDP + seg);
    d[0] = r0; d[1] = r1; d[2] = r2; d[3] = r3;
}

// Copy padded LDS 64x64 back to global (row-major contiguous).
__device__ __forceinline__ void unstage64(float* __restrict__ dst, const float* __restrict__ src, int t) {
    const int i = t >> 2;
    const int seg = (t & 3) << 4;
    const float4* s4 = reinterpret_cast<const float4*>(src + i * LDP + seg);
    float4 r0 = s4[0], r1 = s4[1], r2 = s4[2], r3 = s4[3];
    float4* d = reinterpret_cast<float4*>(dst + i * 64 + seg);
    d[0] = r0; d[1] = r1; d[2] = r2; d[3] = r3;
}

__device__ __forceinline__ void fma_row(float (&acc)[4], float s, const float4& b) {
    acc[0] += s * b.x; acc[1] += s * b.y; acc[2] += s * b.z; acc[3] += s * b.w;
}

// S <- Qn @ S  (both 64x64 in padded LDS). 256 threads, 4x4 tile each.
// Caller must __syncthreads() between staging Qn and calling this.
// On return, S has been rewritten; caller must __syncthreads() before reading S.
__device__ __forceinline__ void mm64(float* __restrict__ S, const float* __restrict__ Qn, int t) {
    const int tx = t & 15, ty = t >> 4;
    const int i0 = ty << 2;   // output rows i0..i0+3
    const int j0 = tx << 2;   // output cols j0..j0+3
    float acc[4][4];
#pragma unroll
    for (int r = 0; r < 4; ++r)
#pragma unroll
        for (int c = 0; c < 4; ++c) acc[r][c] = 0.f;

#pragma unroll
    for (int k4 = 0; k4 < 16; ++k4) {
        const int k = k4 << 2;
        float4 a0 = *reinterpret_cast<const float4*>(&Qn[(i0 + 0) * LDP + k]);
        float4 a1 = *reinterpret_cast<const float4*>(&Qn[(i0 + 1) * LDP + k]);
        float4 a2 = *reinterpret_cast<const float4*>(&Qn[(i0 + 2) * LDP + k]);
        float4 a3 = *reinterpret_cast<const float4*>(&Qn[(i0 + 3) * LDP + k]);
        float4 b0 = *reinterpret_cast<const float4*>(&S[(k + 0) * LDP + j0]);
        float4 b1 = *reinterpret_cast<const float4*>(&S[(k + 1) * LDP + j0]);
        float4 b2 = *reinterpret_cast<const float4*>(&S[(k + 2) * LDP + j0]);
        float4 b3 = *reinterpret_cast<const float4*>(&S[(k + 3) * LDP + j0]);
        fma_row(acc[0], a0.x, b0); fma_row(acc[0], a0.y, b1); fma_row(acc[0], a0.z, b2); fma_row(acc[0], a0.w, b3);
        fma_row(acc[1], a1.x, b0); fma_row(acc[1], a1.y, b1); fma_row(acc[1], a1.z, b2); fma_row(acc[1], a1.w, b3);
        fma_row(acc[2], a2.x, b0); fma_row(acc[2], a2.y, b1); fma_row(acc[2], a2.z, b2); fma_row(acc[2], a2.w, b3);
        fma_row(acc[3], a3.x, b0); fma_row(acc[3], a3.y, b1); fma_row(acc[3], a3.z, b2); fma_row(acc[3], a3.w, b3);
    }
    __syncthreads();   // everyone done READING S before we overwrite it
#pragma unroll
    for (int r = 0; r < 4; ++r) {
        *reinterpret_cast<float4*>(&S[(i0 + r) * LDP + j0]) =
            make_float4(acc[r][0], acc[r][1], acc[r][2], acc[r][3]);
    }
}

// ---------------- Kernel 1: Householder QR (LAPACK sgeqr2 + sorg2r convention) ----------------
// 60 blocks x 256 threads; one 64x64 matrix per block. Writes Q to qtab.
__global__ __launch_bounds__(256) void qr_kernel(const float* __restrict__ repr, float* __restrict__ qtab) {
    __shared__ float A[64 * LDP];
    __shared__ float Qm[64 * LDP];
    __shared__ float taus[64];
    __shared__ float wbuf[4 * 64];
    __shared__ float wfull[64];

    const int t = threadIdx.x;
    const int v = blockIdx.x;
    const int lane = t & 63;
    const int wave = t >> 6;

    stage64(A, repr + v * 4096, t);
    __syncthreads();

    // ---- factorization: 64 Householder steps ----
    for (int k = 0; k < 64; ++k) {
        if (wave == 0) {
            // norm of A[k+1..63][k] via 64-lane butterfly
            float x = (lane > k) ? A[lane * LDP + k] : 0.f;
            float sig = x * x;
#pragma unroll
            for (int off = 32; off; off >>= 1) sig += __shfl_xor(sig, off);
            float alpha = A[k * LDP + k];
            float beta, tau, scl;
            if (sig == 0.f) { beta = alpha; tau = 0.f; scl = 0.f; }
            else {
                beta = -copysignf(sqrtf(alpha * alpha + sig), alpha);
                tau = (beta - alpha) / beta;
                scl = 1.f / (alpha - beta);
            }
            // store v (normalized, v_k=1 implicit) in the column; R_kk=beta on diagonal
            if (lane == k)      A[lane * LDP + k] = beta;
            else if (lane > k)  A[lane * LDP + k] *= scl;
            if (lane == 0) taus[k] = tau;
        }
        __syncthreads();
        // w_j = v^T A[:,j] for trailing columns, 4-way split over waves
        {
            const int j = lane;
            float part = 0.f;
            if (j > k) {
                for (int i = k + wave; i < 64; i += 4) {
                    float vi = (i == k) ? 1.f : A[i * LDP + k];
                    part += vi * A[i * LDP + j];
                }
            }
            wbuf[wave * 64 + j] = part;
        }
        __syncthreads();
        if (t < 64 && t > k)
            wfull[t] = taus[k] * (wbuf[t] + wbuf[64 + t] + wbuf[128 + t] + wbuf[192 + t]);
        __syncthreads();
        {
            const int j = lane;
            if (j > k) {
                const float wj = wfull[j];
                for (int i = k + wave; i < 64; i += 4) {
                    float vi = (i == k) ? 1.f : A[i * LDP + k];
                    A[i * LDP + j] -= vi * wj;
                }
            }
        }
        __syncthreads();
    }

    // ---- form Q = H_0 H_1 ... H_63 (back-accumulation) ----
    for (int e = t; e < 4096; e += 256) {
        int i = e >> 6, j = e & 63;
        Qm[i * LDP + j] = (i == j) ? 1.f : 0.f;
    }
    __syncthreads();
    for (int k = 63; k >= 0; --k) {
        const float tau = taus[k];
        {
            const int j = lane;
            float part = 0.f;
            for (int i = k + wave; i < 64; i += 4) {
                float vi = (i == k) ? 1.f : A[i * LDP + k];
                part += vi * Qm[i * LDP + j];
            }
            wbuf[wave * 64 + j] = part;
        }
        __syncthreads();
        if (t < 64)
            wfull[t] = tau * (wbuf[t] + wbuf[64 + t] + wbuf[128 + t] + wbuf[192 + t]);
        __syncthreads();
        {
            const int j = lane;
            const float wj = wfull[j];
            for (int i = k + wave; i < 64; i += 4) {
                float vi = (i == k) ? 1.f : A[i * LDP + k];
                Qm[i * LDP + j] -= vi * wj;
            }
        }
        __syncthreads();
    }
    unstage64(qtab + v * 4096, Qm, t);
}

// ---------------- Kernel 2: chunk products of 16 consecutive Q's ----------------
// grid = B*32 = 1024 blocks; block (b,c) computes P[b][c] = Q[id(16c+15)] @ ... @ Q[id(16c)]
__global__ __launch_bounds__(256) void scan1_kernel(const int* __restrict__ ids,
                                                    const float* __restrict__ qtab,
                                                    float* __restrict__ P) {
    __shared__ float S[64 * LDP];
    __shared__ float Qn[64 * LDP];
    __shared__ int ids_s[16];
    const int t = threadIdx.x;
    const int b = blockIdx.x >> 5;
    const int c = blockIdx.x & 31;
    if (t < 16) ids_s[t] = ids[(b << 9) + (c << 4) + t];
    __syncthreads();
    stage64(S, qtab + ids_s[0] * 4096, t);
    for (int m = 1; m < 16; ++m) {
        stage64(Qn, qtab + ids_s[m] * 4096, t);
        __syncthreads();
        mm64(S, Qn, t);
    }
    __syncthreads();
    unstage64(P + (blockIdx.x) * 4096, S, t);
}

// ---------------- Kernel 3: products of 8 chunk-products ----------------
// grid = B*4 = 128 blocks; block (b,g) computes PP[b][g] = P[b][8g+7] @ ... @ P[b][8g]
__global__ __launch_bounds__(256) void scan2_kernel(const float* __restrict__ P,
                                                    float* __restrict__ PP) {
    __shared__ float S[64 * LDP];
    __shared__ float Qn[64 * LDP];
    const int t = threadIdx.x;
    const int b = blockIdx.x >> 2;
    const int g = blockIdx.x & 3;
    const float* base = P + (size_t)(b * 32 + g * 8) * 4096;
    stage64(S, base, t);
    for (int m = 1; m < 8; ++m) {
        stage64(Qn, base + m * 4096, t);
        __syncthreads();
        mm64(S, Qn, t);
    }
    __syncthreads();
    unstage64(PP + (size_t)blockIdx.x * 4096, S, t);
}

// ---------------- Kernel 4: final 4-way product + readout ----------------
// grid = 32 blocks; S_b = PP[b][3] @ PP[b][2] @ PP[b][1] @ PP[b][0]; then
// h = relu(vec(S) @ W1 + b1); logits = h @ W2 + b2
__global__ __launch_bounds__(256) void scan3_readout_kernel(const float* __restrict__ PP,
                                                            const float* __restrict__ W1,
                                                            const float* __restrict__ b1,
                                                            const float* __restrict__ W2,
                                                            const float* __restrict__ b2,
                                                            float* __restrict__ out) {
    __shared__ float S[64 * LDP];
    __shared__ float Qn[64 * LDP];
    __shared__ float hl[64];
    const int t = threadIdx.x;
    const int b = blockIdx.x;
    const float* base = PP + (size_t)b * 4 * 4096;
    stage64(S, base, t);
    for (int m = 1; m < 4; ++m) {
        stage64(Qn, base + m * 4096, t);
        __syncthreads();
        mm64(S, Qn, t);
    }
    __syncthreads();

    // h_j = relu(b1[j] + sum_n v[n] * W1[n][j]);  v[n] = S[n>>6][n&63]
    const int jg = t & 15;        // j block: columns 4*jg..4*jg+3
    const int q  = t >> 4;        // n range: q*256 .. q*256+255
    float hp[4] = {0.f, 0.f, 0.f, 0.f};
    const int j4 = jg << 2;
#pragma unroll 4
    for (int m = 0; m < 256; ++m) {
        const int n = (q << 8) + m;
        const float vn = S[(n >> 6) * LDP + (n & 63)];
        const float4 w = *reinterpret_cast<const float4*>(&W1[n * 64 + j4]);
        hp[0] += vn * w.x; hp[1] += vn * w.y; hp[2] += vn * w.z; hp[3] += vn * w.w;
    }
    float* hpart = Qn;  // reuse as scratch: [16][64]
    *reinterpret_cast<float4*>(&hpart[q * 64 + j4]) = make_float4(hp[0], hp[1], hp[2], hp[3]);
    __syncthreads();
    if (t < 64) {
        float h = b1[t];
#pragma unroll
        for (int q2 = 0; q2 < 16; ++q2) h += hpart[q2 * 64 + t];
        hl[t] = fmaxf(h, 0.f);
    }
    __syncthreads();
    if (t < 60) {
        float acc = b2[t];
#pragma unroll
        for (int j = 0; j < 64; ++j) acc += hl[j] * W2[j * 60 + t];
        out[b * 60 + t] = acc;
    }
}

// ---------------- launch ----------------
extern "C" void kernel_launch(void* const* d_in, const int* in_sizes, int n_in,
                              void* d_out, int out_size, void* d_ws, size_t ws_size,
                              hipStream_t stream) {
    (void)in_sizes; (void)n_in; (void)out_size; (void)ws_size;
    const int*   ids  = (const int*)d_in[0];
    const float* repr = (const float*)d_in[1];
    const float* W1   = (const float*)d_in[2];
    const float* b1   = (const float*)d_in[3];
    const float* W2   = (const float*)d_in[4];
    const float* b2   = (const float*)d_in[5];
    float* out = (float*)d_out;

    char* ws = (char*)d_ws;
    float* qtab = (float*)(ws);                              // 60*4096*4  = 0.94 MB
    float* P    = (float*)(ws + (1u << 20));                 // 1024*4096*4 = 16 MB
    float* PP   = (float*)(ws + (1u << 20) + (16u << 20));   // 128*4096*4  = 2 MB

    qr_kernel<<<60, 256, 0, stream>>>(repr, qtab);
    scan1_kernel<<<1024, 256, 0, stream>>>(ids, qtab, P);
    scan2_kernel<<<128, 256, 0, stream>>>(P, PP);
    scan3_readout_kernel<<<32, 256, 0, stream>>>(PP, W1, b1, W2, b2, out);
}